// Round 8
// baseline (12750.909 us; speedup 1.0000x reference)
//
#include <hip/hip_runtime.h>
#include <math.h>

// forecastRNN on MI355X, round 8.
// REVERT round-7 fusion (cross-role contention + worst-role VGPR + L2
// invalidate storms -> 11 ms). Keep its two good pieces as SEPARATE kernels:
// - autoenc_stream: 256 blocks, A-tile in LDS, W register-direct 4-slot ring,
//   3 row-local stages through block-private global scratch. Weights stay
//   L2-hot per XCD (32 blocks share 4 MB). Seed (tau==63) produced here.
// - decode_persistent: round-6 structure, but handoff via PER-PRODUCER flag
//   words 64 B apart (release store, no line contention) + lane-parallel
//   relaxed poll (64 lanes, one IC round trip) + single acquire. This removes
//   the ~13 us/handoff producer-RMW serialization seen in rounds 5/6.

typedef unsigned short ushort_t;
typedef __attribute__((ext_vector_type(8))) short short8;
typedef __attribute__((ext_vector_type(4))) float f32x4;

#define BB 512
#define TT 65
#define TN 64
#define FF 512
#define HD 1000
#define HDP 1024
#define EPSBN 1e-5f
#define BF (BB*FF)          // 262144
#define MALL (BB*TN)        // 32768
#define HP 520              // decode LDS W row stride
#define APW 1032            // autoenc LDS A row stride

__device__ __forceinline__ ushort_t f2bf(float f) {
    union { float f; unsigned u; } v; v.f = f;
    unsigned r = v.u + 0x7FFFu + ((v.u >> 16) & 1u);
    return (ushort_t)(r >> 16);
}

__device__ __forceinline__ float ftanh(float x) {
    const float e = __expf(2.f * x);
    return 1.f - 2.f / (e + 1.f);
}

// ---------------------------------------------------------------------------
// Streaming GEMM pass: acc[4][4] (64 rows x 64 cols) over K=KS.
// A from LDS (row stride AP), W [N x KS] register-direct, 4-slot ring.
// ---------------------------------------------------------------------------
__device__ __forceinline__ void stream_pass(
    const ushort_t* Alds, int AP,
    const ushort_t* __restrict__ W, int n0, int KS,
    f32x4 (&acc)[4][4])
{
    const int lane = threadIdx.x & 63;
    const int lr = lane & 15, lk = (lane >> 4) * 8;
    const int NCH = KS >> 5;
    const ushort_t* wbase = W + (size_t)(n0 + lr) * KS + lk;
    const ushort_t* abase = Alds + lr * AP + lk;
    short8 wr[4][4], ar[2][4];
#pragma unroll
    for (int s = 0; s < 3; ++s)
#pragma unroll
        for (int nt = 0; nt < 4; ++nt)
            wr[s][nt] = *(const short8*)(wbase + (size_t)nt * 16 * KS + s * 32);
#pragma unroll
    for (int mt = 0; mt < 4; ++mt)
        ar[0][mt] = *(const short8*)(abase + mt * 16 * AP);
    for (int kc = 0; kc < NCH; ++kc) {
        if (kc + 3 < NCH) {
            const int sl = (kc + 3) & 3;
#pragma unroll
            for (int nt = 0; nt < 4; ++nt)
                wr[sl][nt] = *(const short8*)(wbase + (size_t)nt * 16 * KS + (kc + 3) * 32);
        }
        if (kc + 1 < NCH) {
#pragma unroll
            for (int mt = 0; mt < 4; ++mt)
                ar[(kc + 1) & 1][mt] = *(const short8*)(abase + mt * 16 * AP + (kc + 1) * 32);
        }
        const int ws = kc & 3, as = kc & 1;
#pragma unroll
        for (int mt = 0; mt < 4; ++mt)
#pragma unroll
            for (int nt = 0; nt < 4; ++nt)
                acc[mt][nt] = __builtin_amdgcn_mfma_f32_16x16x32_bf16(
                    ar[as][mt], wr[ws][nt], acc[mt][nt], 0, 0, 0);
    }
}

__device__ __forceinline__ float bnv(float acc, int col,
    const float* __restrict__ b, const float* __restrict__ rm,
    const float* __restrict__ rv, const float* __restrict__ gg,
    const float* __restrict__ be, int Nreal)
{
    if (col >= Nreal) return 0.f;
    const float s = gg[col] * rsqrtf(rv[col] + EPSBN);
    return (acc + b[col] - rm[col]) * s + be[col];
}

// fill 64-row A tile into LDS (row stride AP), contiguous source rows
__device__ __forceinline__ void fill_a64(const ushort_t* __restrict__ src,
                                         long rs, int KS, ushort_t* Alds, int AP)
{
    const int perrow = KS >> 3;
    const int total = 64 * perrow;
    for (int c = threadIdx.x; c < total; c += 256) {
        const int row = c / perrow, col = (c - row * perrow) * 8;
        *(uint4*)&Alds[row * AP + col] = *(const uint4*)(src + (size_t)row * rs + col);
    }
}

// ---------------------------------------------------------------------------
// XW = x @ Wih^T + b_ih + b_hh -> fp32, streaming, on-the-fly bf16 staging
// ---------------------------------------------------------------------------
__global__ __launch_bounds__(256, 1)
void xw_stream(const float* __restrict__ x, const ushort_t* __restrict__ Wih,
               const float* __restrict__ b_ih, const float* __restrict__ b_hh,
               float* __restrict__ XW)
{
    __shared__ ushort_t Alds[64 * 520];
    const int tid = threadIdx.x, wave = tid >> 6, lane = tid & 63;
    const int lr = lane & 15, rq = (lane >> 4) * 4;
    const int m0 = blockIdx.x * 64;
    for (int c = tid; c < 64 * 64; c += 256) {
        const int row = c >> 6, col = (c & 63) * 8;
        const int m = m0 + row, b = m >> 6, t = m & 63;
        const float* src = x + ((size_t)b * TT + t) * FF + col;
        const float4 v0 = *(const float4*)src;
        const float4 v1 = *(const float4*)(src + 4);
        uint4 o;
        o.x = (unsigned)f2bf(v0.x) | ((unsigned)f2bf(v0.y) << 16);
        o.y = (unsigned)f2bf(v0.z) | ((unsigned)f2bf(v0.w) << 16);
        o.z = (unsigned)f2bf(v1.x) | ((unsigned)f2bf(v1.y) << 16);
        o.w = (unsigned)f2bf(v1.z) | ((unsigned)f2bf(v1.w) << 16);
        *(uint4*)&Alds[row * 520 + col] = o;
    }
    __syncthreads();
    for (int pass = 0; pass < 2; ++pass) {
        const int n0 = wave * 128 + pass * 64;
        f32x4 acc[4][4] = {};
        stream_pass(Alds, 520, Wih, n0, FF, acc);
#pragma unroll
        for (int mt = 0; mt < 4; ++mt)
#pragma unroll
            for (int nt = 0; nt < 4; ++nt) {
                const int col = n0 + nt * 16 + lr;
                const float bb = b_ih[col] + b_hh[col];
#pragma unroll
                for (int r = 0; r < 4; ++r)
                    XW[(size_t)(m0 + mt * 16 + rq + r) * FF + col] = acc[mt][nt][r] + bb;
            }
    }
}

// ---------------------------------------------------------------------------
// Persistent recurrence (round-6 proven): 32 blocks x 16 batch rows.
// ---------------------------------------------------------------------------
__global__ __launch_bounds__(256)
void rnn_persistent(const ushort_t* __restrict__ Whh,
                    const float* __restrict__ XW,
                    ushort_t* __restrict__ hs)
{
    __shared__ ushort_t hb[2][16 * HP];
    const int tid = threadIdx.x, wave = tid >> 6, lane = tid & 63;
    const int b0 = blockIdx.x * 16;
    const int lr = lane & 15, lq = lane >> 4;
    const int c0 = wave * 128;

    for (int it = 0; it < 8; ++it) {
        const int e = (it * 256 + tid) * 4;
        const int row = e >> 9, col = e & 511;
        const size_t gi = ((size_t)(b0 + row) * TN) * FF + col;
        const float4 v = *(const float4*)&XW[gi];
        const ushort_t h0 = f2bf(ftanh(v.x)), h1 = f2bf(ftanh(v.y));
        const ushort_t h2 = f2bf(ftanh(v.z)), h3 = f2bf(ftanh(v.w));
        hb[0][row * HP + col + 0] = h0; hb[0][row * HP + col + 1] = h1;
        hb[0][row * HP + col + 2] = h2; hb[0][row * HP + col + 3] = h3;
        unsigned r0 = (unsigned)h0 | ((unsigned)h1 << 16);
        unsigned r1 = (unsigned)h2 | ((unsigned)h3 << 16);
        *(uint2*)&hs[gi] = make_uint2(r0, r1);
    }
    __syncthreads();

    f32x4 acc[8];
    short8 wf[3][8];
    short8 af[3];
    float xw[8][4];

    for (int t = 1; t < TN; ++t) {
        const ushort_t* hcur = hb[(t - 1) & 1];
#pragma unroll
        for (int s = 0; s < 2; ++s) {
            const int kk = s * 32 + lq * 8;
            af[s] = *(const short8*)&hcur[lr * HP + kk];
#pragma unroll
            for (int j = 0; j < 8; ++j)
                wf[s][j] = *(const short8*)(Whh + (size_t)(c0 + j * 16 + lr) * FF + kk);
        }
#pragma unroll
        for (int j = 0; j < 8; ++j)
#pragma unroll
            for (int r = 0; r < 4; ++r)
                xw[j][r] = XW[((size_t)(b0 + lq * 4 + r) * TN + t) * FF
                              + c0 + j * 16 + lr];
#pragma unroll
        for (int j = 0; j < 8; ++j) acc[j] = (f32x4){0.f, 0.f, 0.f, 0.f};

#pragma unroll
        for (int kc = 0; kc < 16; ++kc) {
            if (kc + 2 < 16) {
                const int slot = (kc + 2) % 3;
                const int kk = (kc + 2) * 32 + lq * 8;
                af[slot] = *(const short8*)&hcur[lr * HP + kk];
#pragma unroll
                for (int j = 0; j < 8; ++j)
                    wf[slot][j] = *(const short8*)
                        (Whh + (size_t)(c0 + j * 16 + lr) * FF + kk);
            }
            const int b = kc % 3;
#pragma unroll
            for (int j = 0; j < 8; ++j)
                acc[j] = __builtin_amdgcn_mfma_f32_16x16x32_bf16(
                    af[b], wf[b][j], acc[j], 0, 0, 0);
        }

        ushort_t* hnxt = hb[t & 1];
#pragma unroll
        for (int j = 0; j < 8; ++j) {
            const int col = c0 + j * 16 + lr;
#pragma unroll
            for (int r = 0; r < 4; ++r) {
                const int row = lq * 4 + r;
                const size_t gi = ((size_t)(b0 + row) * TN + t) * FF + col;
                const ushort_t hv = f2bf(ftanh(acc[j][r] + xw[j][r]));
                hnxt[row * HP + col] = hv;
                hs[gi] = hv;
            }
        }
        __syncthreads();
    }
}

// ---------------------------------------------------------------------------
// Autoenc: 256 blocks x 128 rows (2 chunks of 64). Standalone, barrier-free.
// Produces loss1 partials + seed (tau==63 rows).
// ---------------------------------------------------------------------------
__global__ __launch_bounds__(256, 1)
void autoenc_stream(const ushort_t* __restrict__ hs, const float* __restrict__ x,
                    const ushort_t* __restrict__ W1b,
                    const ushort_t* __restrict__ W2b,
                    const ushort_t* __restrict__ W3b,
                    ushort_t* __restrict__ z1scr, ushort_t* __restrict__ z2scr,
                    ushort_t* __restrict__ seed, float* __restrict__ sums,
                    const float* __restrict__ b1, const float* __restrict__ rm1,
                    const float* __restrict__ rv1, const float* __restrict__ g1,
                    const float* __restrict__ be1,
                    const float* __restrict__ b2, const float* __restrict__ rm2,
                    const float* __restrict__ rv2, const float* __restrict__ g2,
                    const float* __restrict__ be2,
                    const float* __restrict__ b3, const float* __restrict__ rm3,
                    const float* __restrict__ rv3, const float* __restrict__ g3,
                    const float* __restrict__ be3)
{
    __shared__ ushort_t Alds[64 * APW];   // 132,096 B
    __shared__ float red[256];
    const int wave = threadIdx.x >> 6, lane = threadIdx.x & 63;
    const int lr = lane & 15, rq = (lane >> 4) * 4;
    ushort_t* z1s = z1scr + (size_t)blockIdx.x * 64 * HDP;
    ushort_t* z2s = z2scr + (size_t)blockIdx.x * 64 * HDP;

    for (int cc = 0; cc < 2; ++cc) {
        const int r0 = (blockIdx.x * 2 + cc) * 64;
        // S1: A = h rows (K=512) -> z1
        __syncthreads();
        fill_a64(hs + (size_t)r0 * FF, FF, FF, Alds, APW);
        __syncthreads();
        for (int pass = 0; pass < 4; ++pass) {
            const int n0 = wave * 256 + pass * 64;
            f32x4 acc[4][4] = {};
            stream_pass(Alds, APW, W1b, n0, FF, acc);
#pragma unroll
            for (int mt = 0; mt < 4; ++mt)
#pragma unroll
                for (int nt = 0; nt < 4; ++nt) {
                    const int col = n0 + nt * 16 + lr;
#pragma unroll
                    for (int r = 0; r < 4; ++r)
                        z1s[(size_t)(mt * 16 + rq + r) * HDP + col] =
                            f2bf(bnv(acc[mt][nt][r], col, b1, rm1, rv1, g1, be1, HD));
                }
        }
        // S2: A = z1 (K=1024) -> z2
        __syncthreads();
        fill_a64(z1s, HDP, HDP, Alds, APW);
        __syncthreads();
        for (int pass = 0; pass < 4; ++pass) {
            const int n0 = wave * 256 + pass * 64;
            f32x4 acc[4][4] = {};
            stream_pass(Alds, APW, W2b, n0, HDP, acc);
#pragma unroll
            for (int mt = 0; mt < 4; ++mt)
#pragma unroll
                for (int nt = 0; nt < 4; ++nt) {
                    const int col = n0 + nt * 16 + lr;
#pragma unroll
                    for (int r = 0; r < 4; ++r)
                        z2s[(size_t)(mt * 16 + rq + r) * HDP + col] =
                            f2bf(bnv(acc[mt][nt][r], col, b2, rm2, rv2, g2, be2, HD));
                }
        }
        // S3: A = z2 (K=1024) -> loss1 / seed
        __syncthreads();
        fill_a64(z2s, HDP, HDP, Alds, APW);
        __syncthreads();
        float lsum = 0.f;
        for (int pass = 0; pass < 2; ++pass) {
            const int n0 = wave * 128 + pass * 64;
            f32x4 acc[4][4] = {};
            stream_pass(Alds, APW, W3b, n0, HDP, acc);
#pragma unroll
            for (int mt = 0; mt < 4; ++mt)
#pragma unroll
                for (int nt = 0; nt < 4; ++nt) {
                    const int col = n0 + nt * 16 + lr;
#pragma unroll
                    for (int r = 0; r < 4; ++r) {
                        const int row = mt * 16 + rq + r;
                        const float o = bnv(acc[mt][nt][r], col, b3, rm3, rv3, g3, be3, FF);
                        const int grow = r0 + row, b = grow >> 6, tau = grow & 63;
                        if (tau < 63) {
                            const float d = o - x[((size_t)b * TT + tau + 1) * FF + col];
                            lsum += d * d;
                        } else {
                            seed[(size_t)b * FF + col] = f2bf(o);
                        }
                    }
                }
        }
        red[threadIdx.x] = lsum;
        __syncthreads();
        for (int o = 128; o > 0; o >>= 1) {
            if (threadIdx.x < o) red[threadIdx.x] += red[threadIdx.x + o];
            __syncthreads();
        }
        if (threadIdx.x == 0) atomicAdd(&sums[0], red[0]);
    }
}

// ---------------------------------------------------------------------------
// Decode handoff: per-producer flag words 64 B apart. Producer: syncthreads
// (drains block stores to L2) + RELEASE store (wbl2) to OWN slot. Consumer:
// wave-0 lane-parallel RELAXED poll of all slots + one ACQUIRE + barrier.
// ---------------------------------------------------------------------------
__device__ __forceinline__ void wait_flags(unsigned* __restrict__ base,
                                           int nprod, unsigned tgt)
{
    const int tid = threadIdx.x;
    if (tid < 64) {
        unsigned* p = base + (size_t)(tid & (nprod - 1)) * 16;
        for (;;) {
            const unsigned v = __hip_atomic_load(p, __ATOMIC_RELAXED,
                                                 __HIP_MEMORY_SCOPE_AGENT);
            if (__all(v >= tgt)) break;
            __builtin_amdgcn_s_sleep(1);
        }
        if (tid == 0)
            (void)__hip_atomic_load(base, __ATOMIC_ACQUIRE,
                                    __HIP_MEMORY_SCOPE_AGENT);
    }
    __syncthreads();
}

__device__ __forceinline__ void arrive_flag(unsigned* __restrict__ slot,
                                            unsigned val)
{
    __syncthreads();
    if (threadIdx.x == 0)
        __hip_atomic_store(slot, val, __ATOMIC_RELEASE,
                           __HIP_MEMORY_SCOPE_AGENT);
}

__device__ __forceinline__ void load_wslice(const ushort_t* __restrict__ W,
                                            int n0, int K, int rows,
                                            ushort_t* dst, int wrs)
{
    const int nch = K >> 3;
    const int total = rows * nch;
    for (int c = threadIdx.x; c < total; c += 256) {
        const int row = c / nch, col = (c - row * nch) * 8;
        *(uint4*)&dst[(size_t)row * wrs + col] =
            *(const uint4*)&W[(size_t)(n0 + row) * K + col];
    }
}

template <int MT, int NCH1, int NCH2>
__device__ __forceinline__ void frag_gemm(
    const ushort_t* __restrict__ A1, long a1_rs,
    const ushort_t* __restrict__ A2, long a2_rs,
    const ushort_t* w1, const ushort_t* w2, int wrs,
    int mrow0, f32x4 (&acc)[MT][4])
{
    const int lane = threadIdx.x & 63;
    const int lr = lane & 15, lk = (lane >> 4) * 8;
    constexpr int NCH = NCH1 + NCH2;
    constexpr int PF = 4;
    short8 a[PF][MT];

    auto aload = [&](int kc, int slot) {
        const bool p2 = (kc >= NCH1);
        const ushort_t* Ap = p2 ? A2 : A1;
        const long rs = p2 ? a2_rs : a1_rs;
        const int kk = (p2 ? kc - NCH1 : kc) * 32 + lk;
#pragma unroll
        for (int mt = 0; mt < MT; ++mt)
            a[slot][mt] = *(const short8*)(Ap + (size_t)(mrow0 + mt * 16 + lr) * rs + kk);
    };
#pragma unroll
    for (int p = 0; p < PF - 1; ++p) aload(p, p);
#pragma unroll
    for (int kc = 0; kc < NCH; ++kc) {
        if (kc + PF - 1 < NCH) aload(kc + PF - 1, (kc + PF - 1) % PF);
        const bool p2 = (kc >= NCH1);
        const ushort_t* wl = p2 ? w2 : w1;
        const int kk = (p2 ? kc - NCH1 : kc) * 32 + lk;
        short8 wfr[4];
#pragma unroll
        for (int nt = 0; nt < 4; ++nt)
            wfr[nt] = *(const short8*)&wl[(size_t)(nt * 16 + lr) * wrs + kk];
#pragma unroll
        for (int mt = 0; mt < MT; ++mt)
#pragma unroll
            for (int nt = 0; nt < 4; ++nt)
                acc[mt][nt] = __builtin_amdgcn_mfma_f32_16x16x32_bf16(
                    a[kc % PF][mt], wfr[nt], acc[mt][nt], 0, 0, 0);
    }
}

template <int MT>
__device__ __forceinline__ void ep_tanh(f32x4 (&acc)[MT][4], int mrow0, int gc0,
                                        const float* __restrict__ p1,
                                        const float* __restrict__ p2,
                                        ushort_t* __restrict__ obf, long o_rs)
{
    const int lane = threadIdx.x & 63;
    const int lr = lane & 15, rq = (lane >> 4) * 4;
#pragma unroll
    for (int mt = 0; mt < MT; ++mt)
#pragma unroll
        for (int nt = 0; nt < 4; ++nt) {
            const int gcol = gc0 + nt * 16 + lr;
            const float bb = p1[gcol] + p2[gcol];
#pragma unroll
            for (int r = 0; r < 4; ++r) {
                const int grow = mrow0 + mt * 16 + rq + r;
                obf[(size_t)grow * o_rs + gcol] = f2bf(ftanh(acc[mt][nt][r] + bb));
            }
        }
}

template <int MT>
__device__ __forceinline__ void ep_bn(f32x4 (&acc)[MT][4], int mrow0, int gc0,
                                      const float* __restrict__ b,
                                      const float* __restrict__ rm,
                                      const float* __restrict__ rv,
                                      const float* __restrict__ gg,
                                      const float* __restrict__ be,
                                      int Nreal,
                                      ushort_t* __restrict__ obf, long o_rs,
                                      float* __restrict__ of32)
{
    const int lane = threadIdx.x & 63;
    const int lr = lane & 15, rq = (lane >> 4) * 4;
#pragma unroll
    for (int mt = 0; mt < MT; ++mt)
#pragma unroll
        for (int nt = 0; nt < 4; ++nt) {
            const int gcol = gc0 + nt * 16 + lr;
            const bool ok = gcol < Nreal;
            const float s = ok ? gg[gcol] * rsqrtf(rv[gcol] + EPSBN) : 0.f;
            const float c = ok ? (b[gcol] - rm[gcol]) * s + be[gcol] : 0.f;
#pragma unroll
            for (int r = 0; r < 4; ++r) {
                const int grow = mrow0 + mt * 16 + rq + r;
                const float o = ok ? acc[mt][nt][r] * s + c : 0.f;
                obf[(size_t)grow * o_rs + gcol] = f2bf(o);
                if (of32) of32[(size_t)grow * o_rs + gcol] = o;
            }
        }
}

// ---------------------------------------------------------------------------
// Persistent decode: 224 stage-specialized blocks, weights resident in LDS.
// roles: [0,32) cell, [32,96) L1, [96,160) L2, [160,224) L3.
// Flags: stage s slots at flags + s*64*16 (64 B apart per producer).
// ---------------------------------------------------------------------------
__global__ __launch_bounds__(256)
void decode_persistent(const ushort_t* __restrict__ seed,
                       const ushort_t* __restrict__ hs,
                       const ushort_t* __restrict__ Wih,
                       const ushort_t* __restrict__ Whh,
                       const ushort_t* __restrict__ W1b,
                       const ushort_t* __restrict__ W2b,
                       const ushort_t* __restrict__ W3b,
                       ushort_t* __restrict__ hdec,
                       ushort_t* __restrict__ zd1, ushort_t* __restrict__ zd2,
                       float* __restrict__ xg, ushort_t* __restrict__ xgb,
                       unsigned* __restrict__ flags,
                       const float* __restrict__ b_ih, const float* __restrict__ b_hh,
                       const float* __restrict__ b1, const float* __restrict__ rm1,
                       const float* __restrict__ rv1, const float* __restrict__ g1,
                       const float* __restrict__ be1,
                       const float* __restrict__ b2, const float* __restrict__ rm2,
                       const float* __restrict__ rv2, const float* __restrict__ g2,
                       const float* __restrict__ be2,
                       const float* __restrict__ b3, const float* __restrict__ rm3,
                       const float* __restrict__ rv3, const float* __restrict__ g3,
                       const float* __restrict__ be3)
{
    __shared__ ushort_t wlds[66560];
    const int id = blockIdx.x;
    const int wave = threadIdx.x >> 6;
    unsigned* f_cell = flags;
    unsigned* f_l1   = flags + 64 * 16;
    unsigned* f_l2   = flags + 128 * 16;
    unsigned* f_l3   = flags + 192 * 16;

    if (id < 32) {
        // ---- cell role ----
        const int rg = id >> 3, cg = id & 7;
        unsigned* my = f_cell + (size_t)id * 16;
        load_wslice(Wih, cg * 64, FF, 64, wlds, HP);
        load_wslice(Whh, cg * 64, FF, 64, wlds + 64 * HP, HP);
        __syncthreads();
        for (int g = 0; g < 16; ++g) {
            if (g) wait_flags(f_l3, 64, (unsigned)g);
            const ushort_t* xprev = g ? (xgb + (size_t)(g - 1) * BF) : seed;
            const ushort_t* hprev = g ? (hdec + (size_t)((g - 1) & 1) * BF)
                                      : (hs + (size_t)63 * FF);
            const long h_rs = g ? (long)FF : (long)(TN * FF);
            ushort_t* hnew = hdec + (size_t)(g & 1) * BF;
            const int m0 = rg * 128 + wave * 32;
            f32x4 acc[2][4] = {};
            frag_gemm<2, 16, 16>(xprev, FF, hprev, h_rs,
                                 wlds, wlds + 64 * HP, HP, m0, acc);
            ep_tanh<2>(acc, m0, cg * 64, b_ih, b_hh, hnew, FF);
            arrive_flag(my, (unsigned)(g + 1));
        }
    } else if (id < 96) {
        // ---- L1 role ----
        const int rg = (id - 32) >> 3, cg = (id - 32) & 7;
        unsigned* my = f_l1 + (size_t)(id - 32) * 16;
        load_wslice(W1b, cg * 128, FF, 128, wlds, HP);
        __syncthreads();
        for (int g = 0; g < 16; ++g) {
            wait_flags(f_cell, 32, (unsigned)(g + 1));
            const ushort_t* hnew = hdec + (size_t)(g & 1) * BF;
            const int m0 = rg * 64 + (wave >> 1) * 32;
            const int gc0 = cg * 128 + (wave & 1) * 64;
            f32x4 acc[2][4] = {};
            frag_gemm<2, 16, 0>(hnew, FF, nullptr, 0,
                                wlds + (wave & 1) * 64 * HP, nullptr, HP, m0, acc);
            ep_bn<2>(acc, m0, gc0, b1, rm1, rv1, g1, be1, HD, zd1, HDP, nullptr);
            arrive_flag(my, (unsigned)(g + 1));
        }
    } else if (id < 160) {
        // ---- L2 role ----
        const int rg = (id - 96) >> 4, cg = (id - 96) & 15;
        unsigned* my = f_l2 + (size_t)(id - 96) * 16;
        load_wslice(W2b, cg * 64, HDP, 64, wlds, 1032);
        __syncthreads();
        for (int g = 0; g < 16; ++g) {
            wait_flags(f_l1, 64, (unsigned)(g + 1));
            const int m0 = rg * 128 + wave * 32;
            f32x4 acc[2][4] = {};
            frag_gemm<2, 32, 0>(zd1, HDP, nullptr, 0,
                                wlds, nullptr, 1032, m0, acc);
            ep_bn<2>(acc, m0, cg * 64, b2, rm2, rv2, g2, be2, HD, zd2, HDP, nullptr);
            arrive_flag(my, (unsigned)(g + 1));
        }
    } else {
        // ---- L3 role ----
        const int rg = (id - 160) >> 3, cg = (id - 160) & 7;
        unsigned* my = f_l3 + (size_t)(id - 160) * 16;
        load_wslice(W3b, cg * 64, HDP, 64, wlds, 1032);
        __syncthreads();
        for (int g = 0; g < 16; ++g) {
            wait_flags(f_l2, 64, (unsigned)(g + 1));
            const int m0 = rg * 64 + wave * 16;
            f32x4 acc[1][4] = {};
            frag_gemm<1, 32, 0>(zd2, HDP, nullptr, 0,
                                wlds, nullptr, 1032, m0, acc);
            ep_bn<1>(acc, m0, cg * 64, b3, rm3, rv3, g3, be3, FF,
                     xgb + (size_t)g * BF, FF, xg + (size_t)g * BF);
            arrive_flag(my, (unsigned)(g + 1));
        }
    }
}

// ---------------------------------------------------------------------------
__global__ void conv_all(const float* __restrict__ Wih, const float* __restrict__ Whh,
                         const float* __restrict__ W1, const float* __restrict__ W2,
                         const float* __restrict__ W3,
                         ushort_t* __restrict__ Wihb, ushort_t* __restrict__ Whhb,
                         ushort_t* __restrict__ W1b, ushort_t* __restrict__ W2b,
                         ushort_t* __restrict__ W3b,
                         float* __restrict__ sums, unsigned* __restrict__ flags)
{
    const int i0 = blockIdx.x * blockDim.x + threadIdx.x;
    if (i0 < 2) sums[i0] = 0.f;
    if (i0 < 4096) flags[i0] = 0u;
    const int NTOT = 262144 * 2 + 524288 + 1048576 + 524288;
    for (int i = i0; i < NTOT; i += gridDim.x * blockDim.x) {
        if (i < 262144) {
            Wihb[i] = f2bf(Wih[i]);
        } else if (i < 524288) {
            Whhb[i - 262144] = f2bf(Whh[i - 262144]);
        } else if (i < 1048576) {
            const int j = i - 524288, n = j >> 9, k = j & 511;
            W1b[j] = f2bf(n < HD ? W1[n * 512 + k] : 0.f);
        } else if (i < 2097152) {
            const int j = i - 1048576, n = j >> 10, k = j & 1023;
            W2b[j] = f2bf((n < HD && k < HD) ? W2[n * 1000 + k] : 0.f);
        } else {
            const int j = i - 2097152, n = j >> 10, k = j & 1023;
            W3b[j] = f2bf(k < HD ? W3[n * 1000 + k] : 0.f);
        }
    }
}

__global__ void gather_kernel(const float* __restrict__ xgaps,
                              const int* __restrict__ tgap,
                              const float* __restrict__ x,
                              float* __restrict__ out,
                              float* __restrict__ sums)
{
    const int i = blockIdx.x * blockDim.x + threadIdx.x;
    float s = 0.f;
    if (i < BF) {
        const int b = i >> 9, f = i & (FF - 1);
        const int g = tgap[b] - 1;
        const float v = xgaps[((size_t)g * BB + b) * FF + f];
        out[i] = v;
        const float d = v - x[((size_t)b * TT + (TT - 1)) * FF + f];
        s = d * d;
    }
    __shared__ float red[256];
    red[threadIdx.x] = s;
    __syncthreads();
    for (int o = 128; o > 0; o >>= 1) {
        if (threadIdx.x < o) red[threadIdx.x] += red[threadIdx.x + o];
        __syncthreads();
    }
    if (threadIdx.x == 0) atomicAdd(&sums[1], red[0]);
}

__global__ void finalize_kernel(const float* __restrict__ sums,
                                float* __restrict__ out)
{
    if (threadIdx.x == 0 && blockIdx.x == 0) {
        const double n1 = 63.0 * 512.0 * 512.0;
        const double n2 = 512.0 * 512.0;
        out[BF] = (float)((double)sums[0] / (n1 * n1) +
                          (double)sums[1] / (n2 * n2));
    }
}

extern "C" void kernel_launch(void* const* d_in, const int* in_sizes, int n_in,
                              void* d_out, int out_size, void* d_ws, size_t ws_size,
                              hipStream_t stream)
{
    const float* x    = (const float*)d_in[0];
    const int*   tgap = (const int*)d_in[1];
    const float* W_ih = (const float*)d_in[2];
    const float* W_hh = (const float*)d_in[3];
    const float* b_ih = (const float*)d_in[4];
    const float* b_hh = (const float*)d_in[5];
    const float* W1 = (const float*)d_in[6];
    const float* b1 = (const float*)d_in[7];
    const float* g1 = (const float*)d_in[8];
    const float* be1 = (const float*)d_in[9];
    const float* rm1 = (const float*)d_in[10];
    const float* rv1 = (const float*)d_in[11];
    const float* W2 = (const float*)d_in[12];
    const float* b2 = (const float*)d_in[13];
    const float* g2 = (const float*)d_in[14];
    const float* be2 = (const float*)d_in[15];
    const float* rm2 = (const float*)d_in[16];
    const float* rv2 = (const float*)d_in[17];
    const float* W3 = (const float*)d_in[18];
    const float* b3 = (const float*)d_in[19];
    const float* g3 = (const float*)d_in[20];
    const float* be3 = (const float*)d_in[21];
    const float* rm3 = (const float*)d_in[22];
    const float* rv3 = (const float*)d_in[23];
    float* out = (float*)d_out;

    char* p = (char*)d_ws;
    auto take = [&](size_t bytes) -> char* {
        char* r = p; p += (bytes + 63) & ~(size_t)63; return r;
    };
    float*    XWbuf = (float*)take((size_t)MALL * FF * 4);        // 67.1 MB
    ushort_t* hs    = (ushort_t*)take((size_t)MALL * FF * 2);     // 33.5 MB
    ushort_t* z1scr = (ushort_t*)take((size_t)256 * 64 * HDP * 2);// 33.5 MB
    ushort_t* z2scr = (ushort_t*)take((size_t)256 * 64 * HDP * 2);// 33.5 MB
    float*    xg    = (float*)take((size_t)16 * BF * 4);          // 16.8 MB
    ushort_t* xgb   = (ushort_t*)take((size_t)16 * BF * 2);       //  8.4 MB
    ushort_t* seed  = (ushort_t*)take((size_t)BF * 2);
    ushort_t* hdec  = (ushort_t*)take((size_t)2 * BF * 2);
    ushort_t* zd1   = (ushort_t*)take((size_t)BB * HDP * 2);
    ushort_t* zd2   = (ushort_t*)take((size_t)BB * HDP * 2);
    ushort_t* Wihb  = (ushort_t*)take((size_t)FF * FF * 2);
    ushort_t* Whhb  = (ushort_t*)take((size_t)FF * FF * 2);
    ushort_t* W1b   = (ushort_t*)take((size_t)HDP * FF * 2);
    ushort_t* W2b   = (ushort_t*)take((size_t)HDP * HDP * 2);
    ushort_t* W3b   = (ushort_t*)take((size_t)FF * HDP * 2);
    float*    sums  = (float*)take(16 * 4);
    unsigned* flags = (unsigned*)take(4096 * 4);                  // 16 KB

    const dim3 blk(256);

    // 0) weight conversion + flag/sum zeroing
    conv_all<<<dim3(1024), blk, 0, stream>>>(
        W_ih, W_hh, W1, W2, W3, Wihb, Whhb, W1b, W2b, W3b, sums, flags);

    // 1) XW = x @ W_ih^T + biases
    xw_stream<<<dim3(MALL / 64), blk, 0, stream>>>(x, Wihb, b_ih, b_hh, XWbuf);

    // 2) recurrence
    rnn_persistent<<<dim3(BB / 16), blk, 0, stream>>>(Whhb, XWbuf, hs);

    // 3) autoenc (streaming, standalone) -> loss1 + seed
    autoenc_stream<<<dim3(256), blk, 0, stream>>>(
        hs, x, W1b, W2b, W3b, z1scr, z2scr, seed, sums,
        b1, rm1, rv1, g1, be1,
        b2, rm2, rv2, g2, be2,
        b3, rm3, rv3, g3, be3);

    // 4) decode (persistent, distributed-flag handoffs)
    decode_persistent<<<dim3(224), blk, 0, stream>>>(
        seed, hs, Wihb, Whhb, W1b, W2b, W3b,
        hdec, zd1, zd2, xg, xgb, flags,
        b_ih, b_hh,
        b1, rm1, rv1, g1, be1,
        b2, rm2, rv2, g2, be2,
        b3, rm3, rv3, g3, be3);

    // 5) gather + finalize
    gather_kernel<<<dim3(BF / 256), blk, 0, stream>>>(xg, tgap, x, out, sums);
    finalize_kernel<<<dim3(1), dim3(64), 0, stream>>>(sums, out);
}

// Round 9
// 2670.408 us; speedup vs baseline: 4.7749x; 4.7749x over previous
//
#include <hip/hip_runtime.h>
#include <math.h>

// forecastRNN on MI355X, round 9.
// Round-8 bug: stream_pass's K-loop wasn't #pragma unroll'd; its runtime
// ring indices (wr[sl], ar[as]) forced the W/A register rings into SCRATCH
// (HBM-backed) -> 960 MB WRITE_SIZE and 11.4 ms autoenc. Fix: template the
// K extent, full unroll, compile-time ring indices. (Same defect explains
// round 7's mega_kernel slowness.) Everything else unchanged from round 8.

typedef unsigned short ushort_t;
typedef __attribute__((ext_vector_type(8))) short short8;
typedef __attribute__((ext_vector_type(4))) float f32x4;

#define BB 512
#define TT 65
#define TN 64
#define FF 512
#define HD 1000
#define HDP 1024
#define EPSBN 1e-5f
#define BF (BB*FF)          // 262144
#define MALL (BB*TN)        // 32768
#define HP 520              // decode LDS W row stride
#define APW 1032            // autoenc LDS A row stride

__device__ __forceinline__ ushort_t f2bf(float f) {
    union { float f; unsigned u; } v; v.f = f;
    unsigned r = v.u + 0x7FFFu + ((v.u >> 16) & 1u);
    return (ushort_t)(r >> 16);
}

__device__ __forceinline__ float ftanh(float x) {
    const float e = __expf(2.f * x);
    return 1.f - 2.f / (e + 1.f);
}

// ---------------------------------------------------------------------------
// Streaming GEMM pass: acc[4][4] (64 rows x 64 cols) over K=KSc (template).
// A from LDS (row stride AP), W [N x KSc] register-direct, 4-slot ring.
// FULLY UNROLLED: all ring indices compile-time -> registers, no scratch.
// ---------------------------------------------------------------------------
template <int KSc>
__device__ __forceinline__ void stream_pass(
    const ushort_t* Alds, int AP,
    const ushort_t* __restrict__ W, int n0,
    f32x4 (&acc)[4][4])
{
    const int lane = threadIdx.x & 63;
    const int lr = lane & 15, lk = (lane >> 4) * 8;
    constexpr int NCH = KSc >> 5;
    const ushort_t* wbase = W + (size_t)(n0 + lr) * KSc + lk;
    const ushort_t* abase = Alds + lr * AP + lk;
    short8 wr[4][4], ar[2][4];
#pragma unroll
    for (int s = 0; s < 3; ++s)
#pragma unroll
        for (int nt = 0; nt < 4; ++nt)
            wr[s][nt] = *(const short8*)(wbase + (size_t)nt * 16 * KSc + s * 32);
#pragma unroll
    for (int mt = 0; mt < 4; ++mt)
        ar[0][mt] = *(const short8*)(abase + mt * 16 * AP);
#pragma unroll
    for (int kc = 0; kc < NCH; ++kc) {
        if (kc + 3 < NCH) {
            const int sl = (kc + 3) & 3;
#pragma unroll
            for (int nt = 0; nt < 4; ++nt)
                wr[sl][nt] = *(const short8*)(wbase + (size_t)nt * 16 * KSc + (kc + 3) * 32);
        }
        if (kc + 1 < NCH) {
#pragma unroll
            for (int mt = 0; mt < 4; ++mt)
                ar[(kc + 1) & 1][mt] = *(const short8*)(abase + mt * 16 * AP + (kc + 1) * 32);
        }
        const int ws = kc & 3, as = kc & 1;
#pragma unroll
        for (int mt = 0; mt < 4; ++mt)
#pragma unroll
            for (int nt = 0; nt < 4; ++nt)
                acc[mt][nt] = __builtin_amdgcn_mfma_f32_16x16x32_bf16(
                    ar[as][mt], wr[ws][nt], acc[mt][nt], 0, 0, 0);
    }
}

__device__ __forceinline__ float bnv(float acc, int col,
    const float* __restrict__ b, const float* __restrict__ rm,
    const float* __restrict__ rv, const float* __restrict__ gg,
    const float* __restrict__ be, int Nreal)
{
    if (col >= Nreal) return 0.f;
    const float s = gg[col] * rsqrtf(rv[col] + EPSBN);
    return (acc + b[col] - rm[col]) * s + be[col];
}

// fill 64-row A tile into LDS (row stride AP), contiguous source rows
__device__ __forceinline__ void fill_a64(const ushort_t* __restrict__ src,
                                         long rs, int KS, ushort_t* Alds, int AP)
{
    const int perrow = KS >> 3;
    const int total = 64 * perrow;
    for (int c = threadIdx.x; c < total; c += 256) {
        const int row = c / perrow, col = (c - row * perrow) * 8;
        *(uint4*)&Alds[row * AP + col] = *(const uint4*)(src + (size_t)row * rs + col);
    }
}

// ---------------------------------------------------------------------------
// XW = x @ Wih^T + b_ih + b_hh -> fp32, streaming, on-the-fly bf16 staging
// ---------------------------------------------------------------------------
__global__ __launch_bounds__(256, 1)
void xw_stream(const float* __restrict__ x, const ushort_t* __restrict__ Wih,
               const float* __restrict__ b_ih, const float* __restrict__ b_hh,
               float* __restrict__ XW)
{
    __shared__ ushort_t Alds[64 * 520];
    const int tid = threadIdx.x, wave = tid >> 6, lane = tid & 63;
    const int lr = lane & 15, rq = (lane >> 4) * 4;
    const int m0 = blockIdx.x * 64;
    for (int c = tid; c < 64 * 64; c += 256) {
        const int row = c >> 6, col = (c & 63) * 8;
        const int m = m0 + row, b = m >> 6, t = m & 63;
        const float* src = x + ((size_t)b * TT + t) * FF + col;
        const float4 v0 = *(const float4*)src;
        const float4 v1 = *(const float4*)(src + 4);
        uint4 o;
        o.x = (unsigned)f2bf(v0.x) | ((unsigned)f2bf(v0.y) << 16);
        o.y = (unsigned)f2bf(v0.z) | ((unsigned)f2bf(v0.w) << 16);
        o.z = (unsigned)f2bf(v1.x) | ((unsigned)f2bf(v1.y) << 16);
        o.w = (unsigned)f2bf(v1.z) | ((unsigned)f2bf(v1.w) << 16);
        *(uint4*)&Alds[row * 520 + col] = o;
    }
    __syncthreads();
    for (int pass = 0; pass < 2; ++pass) {
        const int n0 = wave * 128 + pass * 64;
        f32x4 acc[4][4] = {};
        stream_pass<FF>(Alds, 520, Wih, n0, acc);
#pragma unroll
        for (int mt = 0; mt < 4; ++mt)
#pragma unroll
            for (int nt = 0; nt < 4; ++nt) {
                const int col = n0 + nt * 16 + lr;
                const float bb = b_ih[col] + b_hh[col];
#pragma unroll
                for (int r = 0; r < 4; ++r)
                    XW[(size_t)(m0 + mt * 16 + rq + r) * FF + col] = acc[mt][nt][r] + bb;
            }
    }
}

// ---------------------------------------------------------------------------
// Persistent recurrence (round-6 proven): 32 blocks x 16 batch rows.
// ---------------------------------------------------------------------------
__global__ __launch_bounds__(256)
void rnn_persistent(const ushort_t* __restrict__ Whh,
                    const float* __restrict__ XW,
                    ushort_t* __restrict__ hs)
{
    __shared__ ushort_t hb[2][16 * HP];
    const int tid = threadIdx.x, wave = tid >> 6, lane = tid & 63;
    const int b0 = blockIdx.x * 16;
    const int lr = lane & 15, lq = lane >> 4;
    const int c0 = wave * 128;

    for (int it = 0; it < 8; ++it) {
        const int e = (it * 256 + tid) * 4;
        const int row = e >> 9, col = e & 511;
        const size_t gi = ((size_t)(b0 + row) * TN) * FF + col;
        const float4 v = *(const float4*)&XW[gi];
        const ushort_t h0 = f2bf(ftanh(v.x)), h1 = f2bf(ftanh(v.y));
        const ushort_t h2 = f2bf(ftanh(v.z)), h3 = f2bf(ftanh(v.w));
        hb[0][row * HP + col + 0] = h0; hb[0][row * HP + col + 1] = h1;
        hb[0][row * HP + col + 2] = h2; hb[0][row * HP + col + 3] = h3;
        unsigned r0 = (unsigned)h0 | ((unsigned)h1 << 16);
        unsigned r1 = (unsigned)h2 | ((unsigned)h3 << 16);
        *(uint2*)&hs[gi] = make_uint2(r0, r1);
    }
    __syncthreads();

    f32x4 acc[8];
    short8 wf[3][8];
    short8 af[3];
    float xw[8][4];

    for (int t = 1; t < TN; ++t) {
        const ushort_t* hcur = hb[(t - 1) & 1];
#pragma unroll
        for (int s = 0; s < 2; ++s) {
            const int kk = s * 32 + lq * 8;
            af[s] = *(const short8*)&hcur[lr * HP + kk];
#pragma unroll
            for (int j = 0; j < 8; ++j)
                wf[s][j] = *(const short8*)(Whh + (size_t)(c0 + j * 16 + lr) * FF + kk);
        }
#pragma unroll
        for (int j = 0; j < 8; ++j)
#pragma unroll
            for (int r = 0; r < 4; ++r)
                xw[j][r] = XW[((size_t)(b0 + lq * 4 + r) * TN + t) * FF
                              + c0 + j * 16 + lr];
#pragma unroll
        for (int j = 0; j < 8; ++j) acc[j] = (f32x4){0.f, 0.f, 0.f, 0.f};

#pragma unroll
        for (int kc = 0; kc < 16; ++kc) {
            if (kc + 2 < 16) {
                const int slot = (kc + 2) % 3;
                const int kk = (kc + 2) * 32 + lq * 8;
                af[slot] = *(const short8*)&hcur[lr * HP + kk];
#pragma unroll
                for (int j = 0; j < 8; ++j)
                    wf[slot][j] = *(const short8*)
                        (Whh + (size_t)(c0 + j * 16 + lr) * FF + kk);
            }
            const int b = kc % 3;
#pragma unroll
            for (int j = 0; j < 8; ++j)
                acc[j] = __builtin_amdgcn_mfma_f32_16x16x32_bf16(
                    af[b], wf[b][j], acc[j], 0, 0, 0);
        }

        ushort_t* hnxt = hb[t & 1];
#pragma unroll
        for (int j = 0; j < 8; ++j) {
            const int col = c0 + j * 16 + lr;
#pragma unroll
            for (int r = 0; r < 4; ++r) {
                const int row = lq * 4 + r;
                const size_t gi = ((size_t)(b0 + row) * TN + t) * FF + col;
                const ushort_t hv = f2bf(ftanh(acc[j][r] + xw[j][r]));
                hnxt[row * HP + col] = hv;
                hs[gi] = hv;
            }
        }
        __syncthreads();
    }
}

// ---------------------------------------------------------------------------
// Autoenc: 256 blocks x 128 rows (2 chunks of 64). Standalone, barrier-free.
// ---------------------------------------------------------------------------
__global__ __launch_bounds__(256, 1)
void autoenc_stream(const ushort_t* __restrict__ hs, const float* __restrict__ x,
                    const ushort_t* __restrict__ W1b,
                    const ushort_t* __restrict__ W2b,
                    const ushort_t* __restrict__ W3b,
                    ushort_t* __restrict__ z1scr, ushort_t* __restrict__ z2scr,
                    ushort_t* __restrict__ seed, float* __restrict__ sums,
                    const float* __restrict__ b1, const float* __restrict__ rm1,
                    const float* __restrict__ rv1, const float* __restrict__ g1,
                    const float* __restrict__ be1,
                    const float* __restrict__ b2, const float* __restrict__ rm2,
                    const float* __restrict__ rv2, const float* __restrict__ g2,
                    const float* __restrict__ be2,
                    const float* __restrict__ b3, const float* __restrict__ rm3,
                    const float* __restrict__ rv3, const float* __restrict__ g3,
                    const float* __restrict__ be3)
{
    __shared__ ushort_t Alds[64 * APW];   // 132,096 B
    __shared__ float red[256];
    const int wave = threadIdx.x >> 6, lane = threadIdx.x & 63;
    const int lr = lane & 15, rq = (lane >> 4) * 4;
    ushort_t* z1s = z1scr + (size_t)blockIdx.x * 64 * HDP;
    ushort_t* z2s = z2scr + (size_t)blockIdx.x * 64 * HDP;

    for (int cc = 0; cc < 2; ++cc) {
        const int r0 = (blockIdx.x * 2 + cc) * 64;
        // S1: A = h rows (K=512) -> z1
        __syncthreads();
        fill_a64(hs + (size_t)r0 * FF, FF, FF, Alds, APW);
        __syncthreads();
        for (int pass = 0; pass < 4; ++pass) {
            const int n0 = wave * 256 + pass * 64;
            f32x4 acc[4][4] = {};
            stream_pass<FF>(Alds, APW, W1b, n0, acc);
#pragma unroll
            for (int mt = 0; mt < 4; ++mt)
#pragma unroll
                for (int nt = 0; nt < 4; ++nt) {
                    const int col = n0 + nt * 16 + lr;
#pragma unroll
                    for (int r = 0; r < 4; ++r)
                        z1s[(size_t)(mt * 16 + rq + r) * HDP + col] =
                            f2bf(bnv(acc[mt][nt][r], col, b1, rm1, rv1, g1, be1, HD));
                }
        }
        // S2: A = z1 (K=1024) -> z2
        __syncthreads();
        fill_a64(z1s, HDP, HDP, Alds, APW);
        __syncthreads();
        for (int pass = 0; pass < 4; ++pass) {
            const int n0 = wave * 256 + pass * 64;
            f32x4 acc[4][4] = {};
            stream_pass<HDP>(Alds, APW, W2b, n0, acc);
#pragma unroll
            for (int mt = 0; mt < 4; ++mt)
#pragma unroll
                for (int nt = 0; nt < 4; ++nt) {
                    const int col = n0 + nt * 16 + lr;
#pragma unroll
                    for (int r = 0; r < 4; ++r)
                        z2s[(size_t)(mt * 16 + rq + r) * HDP + col] =
                            f2bf(bnv(acc[mt][nt][r], col, b2, rm2, rv2, g2, be2, HD));
                }
        }
        // S3: A = z2 (K=1024) -> loss1 / seed
        __syncthreads();
        fill_a64(z2s, HDP, HDP, Alds, APW);
        __syncthreads();
        float lsum = 0.f;
        for (int pass = 0; pass < 2; ++pass) {
            const int n0 = wave * 128 + pass * 64;
            f32x4 acc[4][4] = {};
            stream_pass<HDP>(Alds, APW, W3b, n0, acc);
#pragma unroll
            for (int mt = 0; mt < 4; ++mt)
#pragma unroll
                for (int nt = 0; nt < 4; ++nt) {
                    const int col = n0 + nt * 16 + lr;
#pragma unroll
                    for (int r = 0; r < 4; ++r) {
                        const int row = mt * 16 + rq + r;
                        const float o = bnv(acc[mt][nt][r], col, b3, rm3, rv3, g3, be3, FF);
                        const int grow = r0 + row, b = grow >> 6, tau = grow & 63;
                        if (tau < 63) {
                            const float d = o - x[((size_t)b * TT + tau + 1) * FF + col];
                            lsum += d * d;
                        } else {
                            seed[(size_t)b * FF + col] = f2bf(o);
                        }
                    }
                }
        }
        red[threadIdx.x] = lsum;
        __syncthreads();
        for (int o = 128; o > 0; o >>= 1) {
            if (threadIdx.x < o) red[threadIdx.x] += red[threadIdx.x + o];
            __syncthreads();
        }
        if (threadIdx.x == 0) atomicAdd(&sums[0], red[0]);
    }
}

// ---------------------------------------------------------------------------
// Decode handoff: per-producer flag words 64 B apart; lane-parallel poll.
// ---------------------------------------------------------------------------
__device__ __forceinline__ void wait_flags(unsigned* __restrict__ base,
                                           int nprod, unsigned tgt)
{
    const int tid = threadIdx.x;
    if (tid < 64) {
        unsigned* p = base + (size_t)(tid & (nprod - 1)) * 16;
        for (;;) {
            const unsigned v = __hip_atomic_load(p, __ATOMIC_RELAXED,
                                                 __HIP_MEMORY_SCOPE_AGENT);
            if (__all(v >= tgt)) break;
            __builtin_amdgcn_s_sleep(1);
        }
        if (tid == 0)
            (void)__hip_atomic_load(base, __ATOMIC_ACQUIRE,
                                    __HIP_MEMORY_SCOPE_AGENT);
    }
    __syncthreads();
}

__device__ __forceinline__ void arrive_flag(unsigned* __restrict__ slot,
                                            unsigned val)
{
    __syncthreads();
    if (threadIdx.x == 0)
        __hip_atomic_store(slot, val, __ATOMIC_RELEASE,
                           __HIP_MEMORY_SCOPE_AGENT);
}

__device__ __forceinline__ void load_wslice(const ushort_t* __restrict__ W,
                                            int n0, int K, int rows,
                                            ushort_t* dst, int wrs)
{
    const int nch = K >> 3;
    const int total = rows * nch;
    for (int c = threadIdx.x; c < total; c += 256) {
        const int row = c / nch, col = (c - row * nch) * 8;
        *(uint4*)&dst[(size_t)row * wrs + col] =
            *(const uint4*)&W[(size_t)(n0 + row) * K + col];
    }
}

template <int MT, int NCH1, int NCH2>
__device__ __forceinline__ void frag_gemm(
    const ushort_t* __restrict__ A1, long a1_rs,
    const ushort_t* __restrict__ A2, long a2_rs,
    const ushort_t* w1, const ushort_t* w2, int wrs,
    int mrow0, f32x4 (&acc)[MT][4])
{
    const int lane = threadIdx.x & 63;
    const int lr = lane & 15, lk = (lane >> 4) * 8;
    constexpr int NCH = NCH1 + NCH2;
    constexpr int PF = 4;
    short8 a[PF][MT];

    auto aload = [&](int kc, int slot) {
        const bool p2 = (kc >= NCH1);
        const ushort_t* Ap = p2 ? A2 : A1;
        const long rs = p2 ? a2_rs : a1_rs;
        const int kk = (p2 ? kc - NCH1 : kc) * 32 + lk;
#pragma unroll
        for (int mt = 0; mt < MT; ++mt)
            a[slot][mt] = *(const short8*)(Ap + (size_t)(mrow0 + mt * 16 + lr) * rs + kk);
    };
#pragma unroll
    for (int p = 0; p < PF - 1; ++p) aload(p, p);
#pragma unroll
    for (int kc = 0; kc < NCH; ++kc) {
        if (kc + PF - 1 < NCH) aload(kc + PF - 1, (kc + PF - 1) % PF);
        const bool p2 = (kc >= NCH1);
        const ushort_t* wl = p2 ? w2 : w1;
        const int kk = (p2 ? kc - NCH1 : kc) * 32 + lk;
        short8 wfr[4];
#pragma unroll
        for (int nt = 0; nt < 4; ++nt)
            wfr[nt] = *(const short8*)&wl[(size_t)(nt * 16 + lr) * wrs + kk];
#pragma unroll
        for (int mt = 0; mt < MT; ++mt)
#pragma unroll
            for (int nt = 0; nt < 4; ++nt)
                acc[mt][nt] = __builtin_amdgcn_mfma_f32_16x16x32_bf16(
                    a[kc % PF][mt], wfr[nt], acc[mt][nt], 0, 0, 0);
    }
}

template <int MT>
__device__ __forceinline__ void ep_tanh(f32x4 (&acc)[MT][4], int mrow0, int gc0,
                                        const float* __restrict__ p1,
                                        const float* __restrict__ p2,
                                        ushort_t* __restrict__ obf, long o_rs)
{
    const int lane = threadIdx.x & 63;
    const int lr = lane & 15, rq = (lane >> 4) * 4;
#pragma unroll
    for (int mt = 0; mt < MT; ++mt)
#pragma unroll
        for (int nt = 0; nt < 4; ++nt) {
            const int gcol = gc0 + nt * 16 + lr;
            const float bb = p1[gcol] + p2[gcol];
#pragma unroll
            for (int r = 0; r < 4; ++r) {
                const int grow = mrow0 + mt * 16 + rq + r;
                obf[(size_t)grow * o_rs + gcol] = f2bf(ftanh(acc[mt][nt][r] + bb));
            }
        }
}

template <int MT>
__device__ __forceinline__ void ep_bn(f32x4 (&acc)[MT][4], int mrow0, int gc0,
                                      const float* __restrict__ b,
                                      const float* __restrict__ rm,
                                      const float* __restrict__ rv,
                                      const float* __restrict__ gg,
                                      const float* __restrict__ be,
                                      int Nreal,
                                      ushort_t* __restrict__ obf, long o_rs,
                                      float* __restrict__ of32)
{
    const int lane = threadIdx.x & 63;
    const int lr = lane & 15, rq = (lane >> 4) * 4;
#pragma unroll
    for (int mt = 0; mt < MT; ++mt)
#pragma unroll
        for (int nt = 0; nt < 4; ++nt) {
            const int gcol = gc0 + nt * 16 + lr;
            const bool ok = gcol < Nreal;
            const float s = ok ? gg[gcol] * rsqrtf(rv[gcol] + EPSBN) : 0.f;
            const float c = ok ? (b[gcol] - rm[gcol]) * s + be[gcol] : 0.f;
#pragma unroll
            for (int r = 0; r < 4; ++r) {
                const int grow = mrow0 + mt * 16 + rq + r;
                const float o = ok ? acc[mt][nt][r] * s + c : 0.f;
                obf[(size_t)grow * o_rs + gcol] = f2bf(o);
                if (of32) of32[(size_t)grow * o_rs + gcol] = o;
            }
        }
}

// ---------------------------------------------------------------------------
// Persistent decode: 224 stage-specialized blocks, weights resident in LDS.
// ---------------------------------------------------------------------------
__global__ __launch_bounds__(256)
void decode_persistent(const ushort_t* __restrict__ seed,
                       const ushort_t* __restrict__ hs,
                       const ushort_t* __restrict__ Wih,
                       const ushort_t* __restrict__ Whh,
                       const ushort_t* __restrict__ W1b,
                       const ushort_t* __restrict__ W2b,
                       const ushort_t* __restrict__ W3b,
                       ushort_t* __restrict__ hdec,
                       ushort_t* __restrict__ zd1, ushort_t* __restrict__ zd2,
                       float* __restrict__ xg, ushort_t* __restrict__ xgb,
                       unsigned* __restrict__ flags,
                       const float* __restrict__ b_ih, const float* __restrict__ b_hh,
                       const float* __restrict__ b1, const float* __restrict__ rm1,
                       const float* __restrict__ rv1, const float* __restrict__ g1,
                       const float* __restrict__ be1,
                       const float* __restrict__ b2, const float* __restrict__ rm2,
                       const float* __restrict__ rv2, const float* __restrict__ g2,
                       const float* __restrict__ be2,
                       const float* __restrict__ b3, const float* __restrict__ rm3,
                       const float* __restrict__ rv3, const float* __restrict__ g3,
                       const float* __restrict__ be3)
{
    __shared__ ushort_t wlds[66560];
    const int id = blockIdx.x;
    const int wave = threadIdx.x >> 6;
    unsigned* f_cell = flags;
    unsigned* f_l1   = flags + 64 * 16;
    unsigned* f_l2   = flags + 128 * 16;
    unsigned* f_l3   = flags + 192 * 16;

    if (id < 32) {
        const int rg = id >> 3, cg = id & 7;
        unsigned* my = f_cell + (size_t)id * 16;
        load_wslice(Wih, cg * 64, FF, 64, wlds, HP);
        load_wslice(Whh, cg * 64, FF, 64, wlds + 64 * HP, HP);
        __syncthreads();
        for (int g = 0; g < 16; ++g) {
            if (g) wait_flags(f_l3, 64, (unsigned)g);
            const ushort_t* xprev = g ? (xgb + (size_t)(g - 1) * BF) : seed;
            const ushort_t* hprev = g ? (hdec + (size_t)((g - 1) & 1) * BF)
                                      : (hs + (size_t)63 * FF);
            const long h_rs = g ? (long)FF : (long)(TN * FF);
            ushort_t* hnew = hdec + (size_t)(g & 1) * BF;
            const int m0 = rg * 128 + wave * 32;
            f32x4 acc[2][4] = {};
            frag_gemm<2, 16, 16>(xprev, FF, hprev, h_rs,
                                 wlds, wlds + 64 * HP, HP, m0, acc);
            ep_tanh<2>(acc, m0, cg * 64, b_ih, b_hh, hnew, FF);
            arrive_flag(my, (unsigned)(g + 1));
        }
    } else if (id < 96) {
        const int rg = (id - 32) >> 3, cg = (id - 32) & 7;
        unsigned* my = f_l1 + (size_t)(id - 32) * 16;
        load_wslice(W1b, cg * 128, FF, 128, wlds, HP);
        __syncthreads();
        for (int g = 0; g < 16; ++g) {
            wait_flags(f_cell, 32, (unsigned)(g + 1));
            const ushort_t* hnew = hdec + (size_t)(g & 1) * BF;
            const int m0 = rg * 64 + (wave >> 1) * 32;
            const int gc0 = cg * 128 + (wave & 1) * 64;
            f32x4 acc[2][4] = {};
            frag_gemm<2, 16, 0>(hnew, FF, nullptr, 0,
                                wlds + (wave & 1) * 64 * HP, nullptr, HP, m0, acc);
            ep_bn<2>(acc, m0, gc0, b1, rm1, rv1, g1, be1, HD, zd1, HDP, nullptr);
            arrive_flag(my, (unsigned)(g + 1));
        }
    } else if (id < 160) {
        const int rg = (id - 96) >> 4, cg = (id - 96) & 15;
        unsigned* my = f_l2 + (size_t)(id - 96) * 16;
        load_wslice(W2b, cg * 64, HDP, 64, wlds, 1032);
        __syncthreads();
        for (int g = 0; g < 16; ++g) {
            wait_flags(f_l1, 64, (unsigned)(g + 1));
            const int m0 = rg * 128 + wave * 32;
            f32x4 acc[2][4] = {};
            frag_gemm<2, 32, 0>(zd1, HDP, nullptr, 0,
                                wlds, nullptr, 1032, m0, acc);
            ep_bn<2>(acc, m0, cg * 64, b2, rm2, rv2, g2, be2, HD, zd2, HDP, nullptr);
            arrive_flag(my, (unsigned)(g + 1));
        }
    } else {
        const int rg = (id - 160) >> 3, cg = (id - 160) & 7;
        unsigned* my = f_l3 + (size_t)(id - 160) * 16;
        load_wslice(W3b, cg * 64, HDP, 64, wlds, 1032);
        __syncthreads();
        for (int g = 0; g < 16; ++g) {
            wait_flags(f_l2, 64, (unsigned)(g + 1));
            const int m0 = rg * 64 + wave * 16;
            f32x4 acc[1][4] = {};
            frag_gemm<1, 32, 0>(zd2, HDP, nullptr, 0,
                                wlds, nullptr, 1032, m0, acc);
            ep_bn<1>(acc, m0, cg * 64, b3, rm3, rv3, g3, be3, FF,
                     xgb + (size_t)g * BF, FF, xg + (size_t)g * BF);
            arrive_flag(my, (unsigned)(g + 1));
        }
    }
}

// ---------------------------------------------------------------------------
__global__ void conv_all(const float* __restrict__ Wih, const float* __restrict__ Whh,
                         const float* __restrict__ W1, const float* __restrict__ W2,
                         const float* __restrict__ W3,
                         ushort_t* __restrict__ Wihb, ushort_t* __restrict__ Whhb,
                         ushort_t* __restrict__ W1b, ushort_t* __restrict__ W2b,
                         ushort_t* __restrict__ W3b,
                         float* __restrict__ sums, unsigned* __restrict__ flags)
{
    const int i0 = blockIdx.x * blockDim.x + threadIdx.x;
    if (i0 < 2) sums[i0] = 0.f;
    if (i0 < 4096) flags[i0] = 0u;
    const int NTOT = 262144 * 2 + 524288 + 1048576 + 524288;
    for (int i = i0; i < NTOT; i += gridDim.x * blockDim.x) {
        if (i < 262144) {
            Wihb[i] = f2bf(Wih[i]);
        } else if (i < 524288) {
            Whhb[i - 262144] = f2bf(Whh[i - 262144]);
        } else if (i < 1048576) {
            const int j = i - 524288, n = j >> 9, k = j & 511;
            W1b[j] = f2bf(n < HD ? W1[n * 512 + k] : 0.f);
        } else if (i < 2097152) {
            const int j = i - 1048576, n = j >> 10, k = j & 1023;
            W2b[j] = f2bf((n < HD && k < HD) ? W2[n * 1000 + k] : 0.f);
        } else {
            const int j = i - 2097152, n = j >> 10, k = j & 1023;
            W3b[j] = f2bf(k < HD ? W3[n * 1000 + k] : 0.f);
        }
    }
}

__global__ void gather_kernel(const float* __restrict__ xgaps,
                              const int* __restrict__ tgap,
                              const float* __restrict__ x,
                              float* __restrict__ out,
                              float* __restrict__ sums)
{
    const int i = blockIdx.x * blockDim.x + threadIdx.x;
    float s = 0.f;
    if (i < BF) {
        const int b = i >> 9, f = i & (FF - 1);
        const int g = tgap[b] - 1;
        const float v = xgaps[((size_t)g * BB + b) * FF + f];
        out[i] = v;
        const float d = v - x[((size_t)b * TT + (TT - 1)) * FF + f];
        s = d * d;
    }
    __shared__ float red[256];
    red[threadIdx.x] = s;
    __syncthreads();
    for (int o = 128; o > 0; o >>= 1) {
        if (threadIdx.x < o) red[threadIdx.x] += red[threadIdx.x + o];
        __syncthreads();
    }
    if (threadIdx.x == 0) atomicAdd(&sums[1], red[0]);
}

__global__ void finalize_kernel(const float* __restrict__ sums,
                                float* __restrict__ out)
{
    if (threadIdx.x == 0 && blockIdx.x == 0) {
        const double n1 = 63.0 * 512.0 * 512.0;
        const double n2 = 512.0 * 512.0;
        out[BF] = (float)((double)sums[0] / (n1 * n1) +
                          (double)sums[1] / (n2 * n2));
    }
}

extern "C" void kernel_launch(void* const* d_in, const int* in_sizes, int n_in,
                              void* d_out, int out_size, void* d_ws, size_t ws_size,
                              hipStream_t stream)
{
    const float* x    = (const float*)d_in[0];
    const int*   tgap = (const int*)d_in[1];
    const float* W_ih = (const float*)d_in[2];
    const float* W_hh = (const float*)d_in[3];
    const float* b_ih = (const float*)d_in[4];
    const float* b_hh = (const float*)d_in[5];
    const float* W1 = (const float*)d_in[6];
    const float* b1 = (const float*)d_in[7];
    const float* g1 = (const float*)d_in[8];
    const float* be1 = (const float*)d_in[9];
    const float* rm1 = (const float*)d_in[10];
    const float* rv1 = (const float*)d_in[11];
    const float* W2 = (const float*)d_in[12];
    const float* b2 = (const float*)d_in[13];
    const float* g2 = (const float*)d_in[14];
    const float* be2 = (const float*)d_in[15];
    const float* rm2 = (const float*)d_in[16];
    const float* rv2 = (const float*)d_in[17];
    const float* W3 = (const float*)d_in[18];
    const float* b3 = (const float*)d_in[19];
    const float* g3 = (const float*)d_in[20];
    const float* be3 = (const float*)d_in[21];
    const float* rm3 = (const float*)d_in[22];
    const float* rv3 = (const float*)d_in[23];
    float* out = (float*)d_out;

    char* p = (char*)d_ws;
    auto take = [&](size_t bytes) -> char* {
        char* r = p; p += (bytes + 63) & ~(size_t)63; return r;
    };
    float*    XWbuf = (float*)take((size_t)MALL * FF * 4);        // 67.1 MB
    ushort_t* hs    = (ushort_t*)take((size_t)MALL * FF * 2);     // 33.5 MB
    ushort_t* z1scr = (ushort_t*)take((size_t)256 * 64 * HDP * 2);// 33.5 MB
    ushort_t* z2scr = (ushort_t*)take((size_t)256 * 64 * HDP * 2);// 33.5 MB
    float*    xg    = (float*)take((size_t)16 * BF * 4);          // 16.8 MB
    ushort_t* xgb   = (ushort_t*)take((size_t)16 * BF * 2);       //  8.4 MB
    ushort_t* seed  = (ushort_t*)take((size_t)BF * 2);
    ushort_t* hdec  = (ushort_t*)take((size_t)2 * BF * 2);
    ushort_t* zd1   = (ushort_t*)take((size_t)BB * HDP * 2);
    ushort_t* zd2   = (ushort_t*)take((size_t)BB * HDP * 2);
    ushort_t* Wihb  = (ushort_t*)take((size_t)FF * FF * 2);
    ushort_t* Whhb  = (ushort_t*)take((size_t)FF * FF * 2);
    ushort_t* W1b   = (ushort_t*)take((size_t)HDP * FF * 2);
    ushort_t* W2b   = (ushort_t*)take((size_t)HDP * HDP * 2);
    ushort_t* W3b   = (ushort_t*)take((size_t)FF * HDP * 2);
    float*    sums  = (float*)take(16 * 4);
    unsigned* flags = (unsigned*)take(4096 * 4);                  // 16 KB

    const dim3 blk(256);

    conv_all<<<dim3(1024), blk, 0, stream>>>(
        W_ih, W_hh, W1, W2, W3, Wihb, Whhb, W1b, W2b, W3b, sums, flags);

    xw_stream<<<dim3(MALL / 64), blk, 0, stream>>>(x, Wihb, b_ih, b_hh, XWbuf);

    rnn_persistent<<<dim3(BB / 16), blk, 0, stream>>>(Whhb, XWbuf, hs);

    autoenc_stream<<<dim3(256), blk, 0, stream>>>(
        hs, x, W1b, W2b, W3b, z1scr, z2scr, seed, sums,
        b1, rm1, rv1, g1, be1,
        b2, rm2, rv2, g2, be2,
        b3, rm3, rv3, g3, be3);

    decode_persistent<<<dim3(224), blk, 0, stream>>>(
        seed, hs, Wihb, Whhb, W1b, W2b, W3b,
        hdec, zd1, zd2, xg, xgb, flags,
        b_ih, b_hh,
        b1, rm1, rv1, g1, be1,
        b2, rm2, rv2, g2, be2,
        b3, rm3, rv3, g3, be3);

    gather_kernel<<<dim3(BF / 256), blk, 0, stream>>>(xg, tgap, x, out, sums);
    finalize_kernel<<<dim3(1), dim3(64), 0, stream>>>(sums, out);
}